// Round 5
// baseline (232.074 us; speedup 1.0000x reference)
//
#include <hip/hip_runtime.h>
#include <hip/hip_bf16.h>

#define BCNT 128
#define NNODE 64
#define HDIM 256
#define DDIM 128
#define KNEI 8
#define NR (BCNT * NNODE)

// transposed bf16 weight-plane element offsets (in elements)
#define OFF1V 0
#define OFF1A 4194304          // + 64*256*256
#define OFF2V 12582912         // + 64*256*512
#define OFF2A 14680064         // + 64*128*256
#define WTOT  16777216         // + 64*128*256

typedef __attribute__((ext_vector_type(8))) short bf16x8;
typedef __attribute__((ext_vector_type(8))) unsigned short ushort8;
typedef __attribute__((ext_vector_type(16))) float f32x16;

__device__ __forceinline__ unsigned short f2bf(float f) {
    union { __hip_bfloat16 b; unsigned short u; } c;
    c.b = __float2bfloat16(f);
    return c.u;
}
__device__ __forceinline__ float bf2f(unsigned short u) {
    union { unsigned short u; __hip_bfloat16 b; } c;
    c.u = u;
    return __bfloat162float(c.b);
}
__device__ __forceinline__ void split2(float f, unsigned short& h, unsigned short& l) {
    h = f2bf(f);
    l = f2bf(f - bf2f(h));
}

// ---------------------------------------------------------------------------
// wsplit: W f32 [n][k][out] -> transposed bf16 hi/lo planes [n][out][k].
// 64x64 tile per block via LDS. grid (64 tiles, 64 n), 256 thr.
// ---------------------------------------------------------------------------
__global__ __launch_bounds__(256) void wsplit(
    const float* __restrict__ VW1, const float* __restrict__ AW1,
    const float* __restrict__ VW2, const float* __restrict__ AW2,
    ushort* __restrict__ WtH, ushort* __restrict__ WtL)
{
    const int n = blockIdx.y;
    const int t = blockIdx.x;
    const float* src; size_t dbase; int K, OUT, tk, to;
    if (t < 16)      { src = VW1 + (size_t)n*65536;  dbase = OFF1V + (size_t)n*65536;  K=256; OUT=256; tk=t>>2;      to=t&3;      }
    else if (t < 48) { src = AW1 + (size_t)n*131072; dbase = OFF1A + (size_t)n*131072; K=512; OUT=256; tk=(t-16)>>2; to=(t-16)&3; }
    else if (t < 56) { src = VW2 + (size_t)n*32768;  dbase = OFF2V + (size_t)n*32768;  K=256; OUT=128; tk=(t-48)>>1; to=(t-48)&1; }
    else             { src = AW2 + (size_t)n*32768;  dbase = OFF2A + (size_t)n*32768;  K=256; OUT=128; tk=(t-56)>>1; to=(t-56)&1; }
    const int k0 = tk*64, o0 = to*64;
    __shared__ float tile[64][65];
    const int tid = threadIdx.x;
    const int rr = tid>>2, cc = (tid&3)*16;
    #pragma unroll
    for (int j=0;j<4;++j){
        float4 v = *(const float4*)(src + (size_t)(k0+rr)*OUT + (o0+cc+j*4));
        tile[rr][cc+j*4+0]=v.x; tile[rr][cc+j*4+1]=v.y;
        tile[rr][cc+j*4+2]=v.z; tile[rr][cc+j*4+3]=v.w;
    }
    __syncthreads();
    const int orow = tid>>2, kc = (tid&3)*16;
    ushort8 h8a, h8b, l8a, l8b;
    #pragma unroll
    for (int j=0;j<8;++j){
        unsigned short hh, ll;
        split2(tile[kc+j][orow], hh, ll);
        h8a[j]=hh; l8a[j]=ll;
        split2(tile[kc+8+j][orow], hh, ll);
        h8b[j]=hh; l8b[j]=ll;
    }
    size_t d = dbase + (size_t)(o0+orow)*K + (k0+kc);
    *(ushort8*)(WtH + d)     = h8a;
    *(ushort8*)(WtH + d + 8) = h8b;
    *(ushort8*)(WtL + d)     = l8a;
    *(ushort8*)(WtL + d + 8) = l8b;
}

// ---------------------------------------------------------------------------
// xsplit: obs/act f32 -> bf16 hi/lo planes [row][k]
// ---------------------------------------------------------------------------
__global__ __launch_bounds__(256) void xsplit(
    const float* __restrict__ obs, const float* __restrict__ act,
    ushort* __restrict__ obsH, ushort* __restrict__ obsL,
    ushort* __restrict__ actH, ushort* __restrict__ actL)
{
    size_t i = ((size_t)blockIdx.x * 256 + threadIdx.x) * 4;
    const size_t NT = (size_t)NR * HDIM;
    const float* src; ushort *dh, *dl;
    if (i < NT) { src = obs; dh = obsH; dl = obsL; }
    else        { i -= NT; src = act; dh = actH; dl = actL; }
    float4 v = *(const float4*)(src + i);
    ushort4 h4, l4;
    split2(v.x, h4.x, l4.x);
    split2(v.y, h4.y, l4.y);
    split2(v.z, h4.z, l4.z);
    split2(v.w, h4.w, l4.w);
    *(ushort4*)(dh + i) = h4;
    *(ushort4*)(dl + i) = l4;
}

// ---------------------------------------------------------------------------
// mlp1_fused: h = X @ W1 + b1, LN+ReLU fused in-register, writes bf16 planes.
// Block: 32 rows x 256 outs, 4 waves x 2 col-tiles. K from pre-split planes.
// grid 512 (64 n x 2 br x 4 bm), XCD-swizzled so bm-siblings share the W panel.
// ---------------------------------------------------------------------------
__global__ __launch_bounds__(256) void mlp1_fused(
    const ushort* __restrict__ obsH, const ushort* __restrict__ obsL,
    const ushort* __restrict__ actH, const ushort* __restrict__ actL,
    const ushort* __restrict__ WtH, const ushort* __restrict__ WtL,
    const float* __restrict__ Vb1, const float* __restrict__ Ab1,
    const float* __restrict__ Vg1, const float* __restrict__ Vbe1,
    const float* __restrict__ Ag1, const float* __restrict__ Abe1,
    ushort* __restrict__ hbVH, ushort* __restrict__ hbVL,
    ushort* __restrict__ hbAH, ushort* __restrict__ hbAL)
{
    const int id = blockIdx.x;
    const int s_ = (id>>3)&3;                  // bm sibling (same XCD slot)
    const int g_ = ((id>>5)<<3)|(id&7);        // 0..127
    const int n  = g_>>1;
    const int br = g_&1;                       // 0=V, 1=A
    const int bm = s_*32;
    const int KD = br ? 512 : 256;

    const int tid = threadIdx.x;
    const int l = tid&63, w_ = tid>>6;
    const int lo32 = l&31, gg = l>>5;

    __shared__ ushort8 xs[2][256];             // [dbuf][(p*4+c)*32+row], 16B each
    __shared__ float2 wsum[8][16];
    __shared__ float2 lnp[32];

    const size_t wtoff = br ? (size_t)OFF1A + (size_t)n*131072
                            : (size_t)OFF1V + (size_t)n*65536;
    const size_t wcol0 = wtoff + (size_t)(w_*64 + lo32)*KD;
    const size_t wcol1 = wtoff + (size_t)(w_*64 + 32 + lo32)*KD;

    const int srow = tid&31, sc = (tid>>5)&3, sp = tid>>7;
    const size_t xgrow = ((size_t)(bm+srow)*NNODE + n)*HDIM;

    f32x16 acc0 = {}; f32x16 acc1 = {};
    ushort8 xcur, xnxt;
    bf16x8 bh0[2], bh1[2], bl0[2], bl1[2];
    bf16x8 nh0[2], nh1[2], nl0[2], nl1[2];

    auto loadX = [&](int k0, ushort8& x){
        const ushort* plane;
        int kk = k0 & 255;
        if (br && k0 >= 256) plane = sp ? actL : actH;
        else                 plane = sp ? obsL : obsH;
        x = *(const ushort8*)(plane + xgrow + kk + sc*8);
    };
    auto loadB = [&](int k0, bf16x8* h0, bf16x8* h1, bf16x8* l0, bf16x8* l1){
        #pragma unroll
        for (int kb=0;kb<2;++kb){
            size_t o0 = wcol0 + k0 + kb*16 + gg*8;
            size_t o1 = wcol1 + k0 + kb*16 + gg*8;
            h0[kb] = *(const bf16x8*)(WtH + o0);
            l0[kb] = *(const bf16x8*)(WtL + o0);
            h1[kb] = *(const bf16x8*)(WtH + o1);
            l1[kb] = *(const bf16x8*)(WtL + o1);
        }
    };

#define MSTEP(K0, BUF, BH0, BH1, BL0, BL1, NH0, NH1, NL0, NL1, XC, XN) { \
    xs[BUF][(sp*4+sc)*32 + srow] = XC; \
    __syncthreads(); \
    if ((K0)+32 < KD) { loadX((K0)+32, XN); loadB((K0)+32, NH0, NH1, NL0, NL1); } \
    _Pragma("unroll") \
    for (int kb=0;kb<2;++kb){ \
        bf16x8 ah = *(const bf16x8*)&xs[BUF][(kb*2+gg)*32 + lo32]; \
        bf16x8 al = *(const bf16x8*)&xs[BUF][(4 + kb*2+gg)*32 + lo32]; \
        acc0 = __builtin_amdgcn_mfma_f32_32x32x16_bf16(ah, BH0[kb], acc0, 0,0,0); \
        acc0 = __builtin_amdgcn_mfma_f32_32x32x16_bf16(ah, BL0[kb], acc0, 0,0,0); \
        acc0 = __builtin_amdgcn_mfma_f32_32x32x16_bf16(al, BH0[kb], acc0, 0,0,0); \
        acc1 = __builtin_amdgcn_mfma_f32_32x32x16_bf16(ah, BH1[kb], acc1, 0,0,0); \
        acc1 = __builtin_amdgcn_mfma_f32_32x32x16_bf16(ah, BL1[kb], acc1, 0,0,0); \
        acc1 = __builtin_amdgcn_mfma_f32_32x32x16_bf16(al, BH1[kb], acc1, 0,0,0); \
    } }

    loadX(0, xcur);
    loadB(0, bh0, bh1, bl0, bl1);
    for (int k0 = 0; k0 < KD; k0 += 64) {
        MSTEP(k0,    0, bh0,bh1,bl0,bl1, nh0,nh1,nl0,nl1, xcur, xnxt);
        MSTEP(k0+32, 1, nh0,nh1,nl0,nl1, bh0,bh1,bl0,bl1, xnxt, xcur);
    }
#undef MSTEP

    // ---- fused LN epilogue ----
    const float* b1p = (br ? Ab1 : Vb1) + (size_t)n*HDIM;
    const float* gp  = br ? Ag1 : Vg1;
    const float* bep = br ? Abe1 : Vbe1;
    const float bias0 = b1p[w_*64 + lo32];
    const float bias1 = b1p[w_*64 + 32 + lo32];
    float v0[16], v1[16], s[16], q[16];
    #pragma unroll
    for (int r=0;r<16;++r){
        v0[r]=acc0[r]+bias0; v1[r]=acc1[r]+bias1;
        s[r]=v0[r]+v1[r]; q[r]=v0[r]*v0[r]+v1[r]*v1[r];
    }
    #pragma unroll
    for (int off=1; off<32; off<<=1){
        #pragma unroll
        for (int r=0;r<16;++r){ s[r]+=__shfl_xor(s[r],off); q[r]+=__shfl_xor(q[r],off); }
    }
    if (lo32==0){
        #pragma unroll
        for (int r=0;r<16;++r) wsum[w_*2+gg][r] = float2{s[r], q[r]};
    }
    __syncthreads();
    if (tid < 32){
        const int row=tid, ggr=(row>>2)&1, r=(row&3)|((row>>3)<<2);
        float ss=0.f, qq=0.f;
        #pragma unroll
        for (int w=0;w<4;++w){ float2 p=wsum[w*2+ggr][r]; ss+=p.x; qq+=p.y; }
        float mu = ss*(1.0f/256.0f);
        float var = qq*(1.0f/256.0f) - mu*mu;
        lnp[row] = float2{mu, rsqrtf(var + 1e-5f)};
    }
    __syncthreads();
    ushort* oH = br ? hbAH : hbVH;
    ushort* oL = br ? hbAL : hbVL;
    const float g0 = gp[w_*64+lo32],    be0 = bep[w_*64+lo32];
    const float g1 = gp[w_*64+32+lo32], be1 = bep[w_*64+32+lo32];
    #pragma unroll
    for (int r=0;r<16;++r){
        const int mm = (r&3)+8*(r>>2)+4*gg;
        float2 p = lnp[mm];
        size_t base = ((size_t)(bm+mm)*NNODE + n)*HDIM + w_*64;
        float y0 = fmaxf((v0[r]-p.x)*p.y*g0 + be0, 0.0f);
        float y1 = fmaxf((v1[r]-p.x)*p.y*g1 + be1, 0.0f);
        unsigned short hh, ll;
        split2(y0, hh, ll); oH[base+lo32]=hh;    oL[base+lo32]=ll;
        split2(y1, hh, ll); oH[base+32+lo32]=hh; oL[base+32+lo32]=ll;
    }
}

// ---------------------------------------------------------------------------
// mlp2: V = hbV @ VW2 + Vb2 ; A likewise. 32 rows x 64 outs, 2 waves, K=256.
// grid 1024 (64 n x 2 cb x 2 br x 4 bm), XCD-swizzled siblings.
// ---------------------------------------------------------------------------
__global__ __launch_bounds__(128) void mlp2_mfma(
    const ushort* __restrict__ hbVH, const ushort* __restrict__ hbVL,
    const ushort* __restrict__ hbAH, const ushort* __restrict__ hbAL,
    const ushort* __restrict__ WtH, const ushort* __restrict__ WtL,
    const float* __restrict__ Vb2, const float* __restrict__ Ab2,
    float* __restrict__ Vout, float* __restrict__ Aout)
{
    const int id = blockIdx.x;
    const int s_ = (id>>3)&3;
    const int g_ = ((id>>5)<<3)|(id&7);        // 0..255
    const int n  = g_>>2;
    const int cb = g_&1;
    const int br = (g_>>1)&1;
    const int bm = s_*32;

    const int tid = threadIdx.x;
    const int l = tid&63, wc = tid>>6;
    const int lo32=l&31, gg=l>>5;

    __shared__ ushort8 xs[2][256];

    const size_t wtoff = (br ? (size_t)OFF2A : (size_t)OFF2V) + (size_t)n*32768;
    const int oW = cb*64 + wc*32 + lo32;
    const size_t wcol = wtoff + (size_t)oW*HDIM;

    const ushort* xH = br ? hbAH : hbVH;
    const ushort* xL = br ? hbAL : hbVL;
    const int srow = tid&31, sc = tid>>5;      // sc 0..3
    const size_t xgrow = ((size_t)(bm+srow)*NNODE + n)*HDIM;

    f32x16 acc = {};
    ushort8 xhc, xlc, xhn, xln;
    bf16x8 bh[2], bl[2], nh[2], nl[2];

    auto loadX2 = [&](int k0, ushort8& xh, ushort8& xl){
        xh = *(const ushort8*)(xH + xgrow + k0 + sc*8);
        xl = *(const ushort8*)(xL + xgrow + k0 + sc*8);
    };
    auto loadB2 = [&](int k0, bf16x8* h, bf16x8* lo){
        #pragma unroll
        for (int kb=0;kb<2;++kb){
            size_t o = wcol + k0 + kb*16 + gg*8;
            h[kb]  = *(const bf16x8*)(WtH + o);
            lo[kb] = *(const bf16x8*)(WtL + o);
        }
    };

#define MSTEP2(K0, BUF, BH, BL, NH, NL, XHC, XLC, XHN, XLN) { \
    xs[BUF][sc*32 + srow] = XHC; \
    xs[BUF][(4+sc)*32 + srow] = XLC; \
    __syncthreads(); \
    if ((K0)+32 < HDIM) { loadX2((K0)+32, XHN, XLN); loadB2((K0)+32, NH, NL); } \
    _Pragma("unroll") \
    for (int kb=0;kb<2;++kb){ \
        bf16x8 ah = *(const bf16x8*)&xs[BUF][(kb*2+gg)*32 + lo32]; \
        bf16x8 al = *(const bf16x8*)&xs[BUF][(4 + kb*2+gg)*32 + lo32]; \
        acc = __builtin_amdgcn_mfma_f32_32x32x16_bf16(ah, BH[kb], acc, 0,0,0); \
        acc = __builtin_amdgcn_mfma_f32_32x32x16_bf16(ah, BL[kb], acc, 0,0,0); \
        acc = __builtin_amdgcn_mfma_f32_32x32x16_bf16(al, BH[kb], acc, 0,0,0); \
    } }

    loadX2(0, xhc, xlc);
    loadB2(0, bh, bl);
    for (int k0 = 0; k0 < HDIM; k0 += 64) {
        MSTEP2(k0,    0, bh,bl, nh,nl, xhc,xlc, xhn,xln);
        MSTEP2(k0+32, 1, nh,nl, bh,bl, xhn,xln, xhc,xlc);
    }
#undef MSTEP2

    const float bias = (br ? Ab2 : Vb2)[(size_t)n*DDIM + oW];
    float* outp = br ? Aout : Vout;
    #pragma unroll
    for (int r=0;r<16;++r){
        const int mm = (r&3)+8*(r>>2)+4*gg;
        outp[((size_t)(bm+mm)*NNODE + n)*DDIM + oW] = acc[r] + bias;
    }
}

// ---------------------------------------------------------------------------
// chi for both Q=V+A and V; one block per (n, b), 128 threads = one per d
// ---------------------------------------------------------------------------
__global__ __launch_bounds__(128) void chi_kernel(
    const float* __restrict__ V, const float* __restrict__ A,
    const int* __restrict__ le, const float* __restrict__ m1,
    const float* __restrict__ m2, float* __restrict__ out)
{
    const int n = blockIdx.x;
    const int b = blockIdx.y;
    const int tid = threadIdx.x;

    __shared__ float sm1[KNEI];
    __shared__ float sm2[KNEI * KNEI];
    __shared__ int   sidx[KNEI + 1];
    __shared__ float pq[2], pv[2];

    if (tid < KNEI) {
        float s = 0.0f;
        #pragma unroll
        for (int hh = 0; hh < 3; ++hh) s += m1[n * 24 + hh * 8 + tid];
        sm1[tid] = s;
    }
    if (tid < 64) {
        int i = tid >> 3, j = tid & 7;
        float s = 0.0f;
        if (j > i) {
            #pragma unroll
            for (int hh = 0; hh < 3; ++hh) s += m2[n * 192 + hh * 64 + tid];
        }
        sm2[tid] = s;
    }
    if (tid < KNEI + 1) sidx[tid] = le[n * 18 + tid];
    __syncthreads();

    const float* Vb_ = V + (size_t)b * (NNODE * DDIM);
    const float* Ab_ = A + (size_t)b * (NNODE * DDIM);
    const int cen = sidx[0];

    float vn[KNEI], qn[KNEI];
    #pragma unroll
    for (int k = 0; k < KNEI; ++k) {
        int nb = sidx[1 + k];
        float vv = Vb_[nb * DDIM + tid];
        float aa = Ab_[nb * DDIM + tid];
        vn[k] = vv;
        qn[k] = vv + aa;
    }

    float sq = 0.0f, sv = 0.0f;
    #pragma unroll
    for (int k = 0; k < KNEI; ++k) { sq += sm1[k] * qn[k]; sv += sm1[k] * vn[k]; }
    #pragma unroll
    for (int i = 0; i < KNEI; ++i) {
        #pragma unroll
        for (int j = i + 1; j < KNEI; ++j) {
            float w = sm2[i * 8 + j];
            sq += w * fminf(qn[i], qn[j]);
            sv += w * fminf(vn[i], vn[j]);
        }
    }

    float Vc = Vb_[cen * DDIM + tid];
    float Ac = Ab_[cen * DDIM + tid];
    float valq = sq * (1.0f / 3.0f) + (Vc + Ac);
    float valv = sv * (1.0f / 3.0f) + Vc;

    #pragma unroll
    for (int o = 32; o; o >>= 1) {
        valq += __shfl_down(valq, o);
        valv += __shfl_down(valv, o);
    }
    if ((tid & 63) == 0) { pq[tid >> 6] = valq; pv[tid >> 6] = valv; }
    __syncthreads();
    if (tid == 0) {
        out[b * NNODE + n]                = (pq[0] + pq[1]) * (1.0f / 128.0f);
        out[BCNT * NNODE + b * NNODE + n] = (pv[0] + pv[1]) * (1.0f / 128.0f);
    }
}

extern "C" void kernel_launch(void* const* d_in, const int* in_sizes, int n_in,
                              void* d_out, int out_size, void* d_ws, size_t ws_size,
                              hipStream_t stream)
{
    const float* obs  = (const float*)d_in[0];
    const float* act  = (const float*)d_in[1];
    const int*   le   = (const int*)  d_in[2];
    const float* VW1  = (const float*)d_in[3];
    const float* Vb1  = (const float*)d_in[4];
    const float* Vg1  = (const float*)d_in[5];
    const float* Vbe1 = (const float*)d_in[6];
    const float* VW2  = (const float*)d_in[7];
    const float* Vb2  = (const float*)d_in[8];
    const float* AW1  = (const float*)d_in[9];
    const float* Ab1  = (const float*)d_in[10];
    const float* Ag1  = (const float*)d_in[11];
    const float* Abe1 = (const float*)d_in[12];
    const float* AW2  = (const float*)d_in[13];
    const float* Ab2  = (const float*)d_in[14];
    const float* m1   = (const float*)d_in[15];
    const float* m2   = (const float*)d_in[16];
    float* out = (float*)d_out;

    const size_t P = (size_t)NR * HDIM;    // 2,097,152 elems per plane
    ushort* WtH  = (ushort*)d_ws;
    ushort* WtL  = WtH + WTOT;
    ushort* obsH = WtL + WTOT;
    ushort* obsL = obsH + P;
    ushort* actH = obsL + P;
    ushort* actL = actH + P;
    ushort* hbVH = actL + P;
    ushort* hbVL = hbVH + P;
    ushort* hbAH = hbVL + P;
    ushort* hbAL = hbAH + P;
    float*  V    = (float*)(hbAL + P);
    float*  A    = V + (size_t)NR * DDIM;

    wsplit<<<dim3(64, 64), dim3(256), 0, stream>>>(VW1, AW1, VW2, AW2, WtH, WtL);
    xsplit<<<dim3(4096), dim3(256), 0, stream>>>(obs, act, obsH, obsL, actH, actL);
    mlp1_fused<<<dim3(512), dim3(256), 0, stream>>>(obsH, obsL, actH, actL, WtH, WtL,
                                                    Vb1, Ab1, Vg1, Vbe1, Ag1, Abe1,
                                                    hbVH, hbVL, hbAH, hbAL);
    mlp2_mfma<<<dim3(1024), dim3(128), 0, stream>>>(hbVH, hbVL, hbAH, hbAL, WtH, WtL,
                                                    Vb2, Ab2, V, A);
    chi_kernel<<<dim3(NNODE, BCNT), dim3(128), 0, stream>>>(V, A, le, m1, m2, out);
}

// Round 6
// 198.700 us; speedup vs baseline: 1.1680x; 1.1680x over previous
//
#include <hip/hip_runtime.h>
#include <hip/hip_bf16.h>

#define BCNT 128
#define NNODE 64
#define HDIM 256
#define DDIM 128
#define KNEI 8
#define NR (BCNT * NNODE)

// frag-plane offsets (ushort elements) inside WFH/WFL
#define OFF1V 0ull
#define OFF1A 4194304ull      // + 64*8*16*512 (V1)
#define OFF2V 12582912ull     // + 64*8*32*512 (A1)
#define OFF2A 14680064ull     // + 64*4*16*512 (V2)
#define WTOT  16777216ull     // + 64*4*16*512 (A2)
#define XPL   2097152ull      // one X plane: 64*4*16*512

typedef __attribute__((ext_vector_type(8))) short bf16x8;
typedef __attribute__((ext_vector_type(8))) unsigned short ushort8;
typedef __attribute__((ext_vector_type(16))) float f32x16;

__device__ __forceinline__ unsigned short f2bf(float f) {
    union { __hip_bfloat16 b; unsigned short u; } c;
    c.b = __float2bfloat16(f);
    return c.u;
}
__device__ __forceinline__ float bf2f(unsigned short u) {
    union { unsigned short u; __hip_bfloat16 b; } c;
    c.u = u;
    return __bfloat162float(c.b);
}
__device__ __forceinline__ void split2(float f, unsigned short& h, unsigned short& l) {
    h = f2bf(f);
    l = f2bf(f - bf2f(h));
}

// ---------------------------------------------------------------------------
// xsplit_frag: X[b][n][k] f32 -> frag-order bf16 hi/lo planes
//   plane[ ((n*4+bt)*16+kt)*64+lane ][8] ; elem = X[bt*32+(lane&31)][n][kt*16+(lane>>5)*8+i]
// grid (256 = n*4+bt, 2 = obs/act), 256 thr
// ---------------------------------------------------------------------------
__global__ __launch_bounds__(256) void xsplit_frag(
    const float* __restrict__ obs, const float* __restrict__ act,
    ushort* __restrict__ obsH, ushort* __restrict__ obsL,
    ushort* __restrict__ actH, ushort* __restrict__ actL)
{
    const int bx = blockIdx.x;
    const int n = bx >> 2, bt = bx & 3;
    const int srcsel = blockIdx.y;
    const float* S = srcsel ? act : obs;
    ushort* DH = srcsel ? actH : obsH;
    ushort* DL = srcsel ? actL : obsL;

    __shared__ float tile[32 * 257];
    const int t = threadIdx.x;
    {
        const int r = t >> 3, cg = (t & 7) * 32;
        const float* row = S + ((size_t)(bt * 32 + r) * NNODE + n) * HDIM + cg;
        #pragma unroll
        for (int j = 0; j < 8; ++j) {
            float4 v = *(const float4*)(row + j * 4);
            tile[r * 257 + cg + j * 4 + 0] = v.x;
            tile[r * 257 + cg + j * 4 + 1] = v.y;
            tile[r * 257 + cg + j * 4 + 2] = v.z;
            tile[r * 257 + cg + j * 4 + 3] = v.w;
        }
    }
    __syncthreads();
    const int lane = t & 63, g = t >> 6;
    #pragma unroll
    for (int jj = 0; jj < 4; ++jj) {
        const int kt = g * 4 + jj;
        ushort8 h8, l8;
        #pragma unroll
        for (int i = 0; i < 8; ++i) {
            float v = tile[(lane & 31) * 257 + kt * 16 + (lane >> 5) * 8 + i];
            unsigned short hh, ll; split2(v, hh, ll);
            h8[i] = hh; l8[i] = ll;
        }
        size_t idx = ((((size_t)n * 4 + bt) * 16 + kt) * 64 + lane) * 8;
        *(ushort8*)(DH + idx) = h8;
        *(ushort8*)(DL + idx) = l8;
    }
}

// ---------------------------------------------------------------------------
// wsplit_frag: W[n][k][out] f32 -> frag-order bf16 hi/lo planes (B-operand)
//   frag (ot,kt): elem = W^T[ot*32+(lane&31)][kt*16+(lane>>5)*8+i]
// grid (64 tiles, 64 n), 256 thr; each block one 64k x 64out tile
// ---------------------------------------------------------------------------
__global__ __launch_bounds__(256) void wsplit_frag(
    const float* __restrict__ VW1, const float* __restrict__ AW1,
    const float* __restrict__ VW2, const float* __restrict__ AW2,
    ushort* __restrict__ WFH, ushort* __restrict__ WFL)
{
    const int n = blockIdx.y;
    const int tt = blockIdx.x;
    const float* src; size_t fb; int OUT, KT, tk, to;
    if (tt < 16)      { src = VW1 + (size_t)n * 65536;  fb = OFF1V / 512 + (size_t)n * 8 * 16; OUT = 256; KT = 16; tk = tt >> 2;        to = tt & 3;        }
    else if (tt < 48) { src = AW1 + (size_t)n * 131072; fb = OFF1A / 512 + (size_t)n * 8 * 32; OUT = 256; KT = 32; tk = (tt - 16) >> 2; to = (tt - 16) & 3; }
    else if (tt < 56) { src = VW2 + (size_t)n * 32768;  fb = OFF2V / 512 + (size_t)n * 4 * 16; OUT = 128; KT = 16; tk = (tt - 48) >> 1; to = (tt - 48) & 1; }
    else              { src = AW2 + (size_t)n * 32768;  fb = OFF2A / 512 + (size_t)n * 4 * 16; OUT = 128; KT = 16; tk = (tt - 56) >> 1; to = (tt - 56) & 1; }

    const int k0 = tk * 64, o0 = to * 64;
    __shared__ float tile[64 * 65];
    const int t = threadIdx.x;
    {
        const int r = t >> 2, cg = (t & 3) * 16;
        const float* row = src + (size_t)(k0 + r) * OUT + o0 + cg;
        #pragma unroll
        for (int j = 0; j < 4; ++j) {
            float4 v = *(const float4*)(row + j * 4);
            tile[r * 65 + cg + j * 4 + 0] = v.x;
            tile[r * 65 + cg + j * 4 + 1] = v.y;
            tile[r * 65 + cg + j * 4 + 2] = v.z;
            tile[r * 65 + cg + j * 4 + 3] = v.w;
        }
    }
    __syncthreads();
    const int lane = t & 63, g = t >> 6;
    const int ol = g >> 1;
    #pragma unroll
    for (int jj = 0; jj < 2; ++jj) {
        const int kl = (g & 1) * 2 + jj;
        ushort8 h8, l8;
        #pragma unroll
        for (int i = 0; i < 8; ++i) {
            float v = tile[(kl * 16 + (lane >> 5) * 8 + i) * 65 + ol * 32 + (lane & 31)];
            unsigned short hh, ll; split2(v, hh, ll);
            h8[i] = hh; l8[i] = ll;
        }
        size_t fi = fb + (size_t)(to * 2 + ol) * KT + (size_t)(tk * 4 + kl);
        size_t idx = (fi * 64 + lane) * 8;
        *(ushort8*)(WFH + idx) = h8;
        *(ushort8*)(WFL + idx) = l8;
    }
}

// ---------------------------------------------------------------------------
// fused_mlp: mlp1 (zero-barrier frag K-loop) + LN/ReLU/split (in-reg) +
//            mlp2 (LDS A-frags, K-split across wave pairs) -> V / A f32.
// Block: 512 thr (8 waves), 32 batch rows x full pipeline. Grid 512.
// ---------------------------------------------------------------------------
__global__ __launch_bounds__(512, 4) void fused_mlp(
    const ushort* __restrict__ obsH, const ushort* __restrict__ obsL,
    const ushort* __restrict__ actH, const ushort* __restrict__ actL,
    const ushort* __restrict__ WFH, const ushort* __restrict__ WFL,
    const float* __restrict__ Vb1, const float* __restrict__ Ab1,
    const float* __restrict__ Vg1, const float* __restrict__ Vbe1,
    const float* __restrict__ Ag1, const float* __restrict__ Abe1,
    const float* __restrict__ Vb2, const float* __restrict__ Ab2,
    float* __restrict__ Vout, float* __restrict__ Aout)
{
    // XCD-grouped decode: the 4 bt-siblings of one (n,br) land on one XCD
    const int id = blockIdx.x;
    const int xcd = id & 7, slot = id >> 3;
    const int bt = slot & 3;
    const int pair = (slot >> 2) * 8 + xcd;     // 0..127
    const int n = pair >> 1, br = pair & 1;

    const int t = threadIdx.x;
    const int l = t & 63, w = t >> 6;
    const int lo = l & 31, gg = l >> 5;

    __shared__ ushort hbtH[32 * 264];
    __shared__ ushort hbtL[32 * 264];
    __shared__ float2 lnS[8][32];
    __shared__ float2 lnp[32];
    __shared__ float red[4][16][64];

    // ---- phase 1: h = X @ W1 (wave w owns out cols w*32..w*32+31) ----
    const int nkt = br ? 32 : 16;
    const size_t wb = (br ? OFF1A + ((size_t)n * 8 + w) * 32 * 512
                          : OFF1V + ((size_t)n * 8 + w) * 16 * 512) + (size_t)l * 8;
    const size_t xb = (((size_t)n * 4 + bt) * 16) * 512 + (size_t)l * 8;

    f32x16 aP = {}, aQ = {};
    #pragma unroll 4
    for (int kt = 0; kt < nkt; ++kt) {
        const ushort* xh; const ushort* xl;
        if (br && kt >= 16) { xh = actH; xl = actL; }
        else                { xh = obsH; xl = obsL; }
        const size_t xi = xb + (size_t)(kt & 15) * 512;
        const size_t wi = wb + (size_t)kt * 512;
        bf16x8 ah = *(const bf16x8*)(xh + xi);
        bf16x8 al = *(const bf16x8*)(xl + xi);
        bf16x8 bh = *(const bf16x8*)(WFH + wi);
        bf16x8 bl = *(const bf16x8*)(WFL + wi);
        aP = __builtin_amdgcn_mfma_f32_32x32x16_bf16(ah, bh, aP, 0, 0, 0);
        aQ = __builtin_amdgcn_mfma_f32_32x32x16_bf16(ah, bl, aQ, 0, 0, 0);
        aQ = __builtin_amdgcn_mfma_f32_32x32x16_bf16(al, bh, aQ, 0, 0, 0);
    }

    // ---- phase 2: LN + ReLU + bf16 split -> LDS hbt ----
    const int col = w * 32 + lo;
    const float b1 = (br ? Ab1 : Vb1)[n * HDIM + col];
    float v[16];
    #pragma unroll
    for (int r = 0; r < 16; ++r) {
        v[r] = aP[r] + aQ[r] + b1;
        float s = v[r], q = v[r] * v[r];
        #pragma unroll
        for (int off = 1; off < 32; off <<= 1) {
            s += __shfl_xor(s, off);
            q += __shfl_xor(q, off);
        }
        if (lo == 0) lnS[w][(r & 3) + 8 * (r >> 2) + 4 * gg] = float2{s, q};
    }
    __syncthreads();
    if (t < 32) {
        float ss = 0.f, qq = 0.f;
        #pragma unroll
        for (int w2 = 0; w2 < 8; ++w2) { ss += lnS[w2][t].x; qq += lnS[w2][t].y; }
        float mu = ss * (1.0f / 256.0f);
        float var = qq * (1.0f / 256.0f) - mu * mu;
        lnp[t] = float2{mu, rsqrtf(var + 1e-5f)};
    }
    __syncthreads();
    {
        const float g1 = (br ? Ag1 : Vg1)[col];
        const float be = (br ? Abe1 : Vbe1)[col];
        #pragma unroll
        for (int r = 0; r < 16; ++r) {
            const int mm = (r & 3) + 8 * (r >> 2) + 4 * gg;
            float2 p = lnp[mm];
            float y = fmaxf((v[r] - p.x) * p.y * g1 + be, 0.0f);
            unsigned short hh, ll; split2(y, hh, ll);
            hbtH[mm * 264 + col] = hh;
            hbtL[mm * 264 + col] = ll;
        }
    }
    __syncthreads();

    // ---- phase 3: out = hb @ W2 (wave: out-tile w&3, K-half w>>2) ----
    const int ot2 = w & 3, kh = w >> 2;
    const size_t w2b = (br ? OFF2A : OFF2V) + ((size_t)n * 4 + ot2) * 16 * 512 + (size_t)l * 8;
    f32x16 cP = {}, cQ = {};
    #pragma unroll
    for (int j = 0; j < 8; ++j) {
        const int kt = kh * 8 + j;
        const int lb = lo * 264 + kt * 16 + gg * 8;
        bf16x8 ah = *(const bf16x8*)&hbtH[lb];
        bf16x8 al = *(const bf16x8*)&hbtL[lb];
        const size_t wi = w2b + (size_t)kt * 512;
        bf16x8 bh = *(const bf16x8*)(WFH + wi);
        bf16x8 bl = *(const bf16x8*)(WFL + wi);
        cP = __builtin_amdgcn_mfma_f32_32x32x16_bf16(ah, bh, cP, 0, 0, 0);
        cQ = __builtin_amdgcn_mfma_f32_32x32x16_bf16(ah, bl, cQ, 0, 0, 0);
        cQ = __builtin_amdgcn_mfma_f32_32x32x16_bf16(al, bh, cQ, 0, 0, 0);
    }
    float c[16];
    #pragma unroll
    for (int r = 0; r < 16; ++r) c[r] = cP[r] + cQ[r];
    if (w >= 4) {
        #pragma unroll
        for (int r = 0; r < 16; ++r) red[w - 4][r][l] = c[r];
    }
    __syncthreads();
    if (w < 4) {
        const float b2 = (br ? Ab2 : Vb2)[n * DDIM + ot2 * 32 + lo];
        float* outp = br ? Aout : Vout;
        #pragma unroll
        for (int r = 0; r < 16; ++r) {
            const int mm = (r & 3) + 8 * (r >> 2) + 4 * gg;
            outp[((size_t)(bt * 32 + mm) * NNODE + n) * DDIM + ot2 * 32 + lo]
                = c[r] + red[w][r][l] + b2;
        }
    }
}

// ---------------------------------------------------------------------------
// chi for both Q=V+A and V; one block per (n, b), 128 threads = one per d
// ---------------------------------------------------------------------------
__global__ __launch_bounds__(128) void chi_kernel(
    const float* __restrict__ V, const float* __restrict__ A,
    const int* __restrict__ le, const float* __restrict__ m1,
    const float* __restrict__ m2, float* __restrict__ out)
{
    const int n = blockIdx.x;
    const int b = blockIdx.y;
    const int tid = threadIdx.x;

    __shared__ float sm1[KNEI];
    __shared__ float sm2[KNEI * KNEI];
    __shared__ int   sidx[KNEI + 1];
    __shared__ float pq[2], pv[2];

    if (tid < KNEI) {
        float s = 0.0f;
        #pragma unroll
        for (int hh = 0; hh < 3; ++hh) s += m1[n * 24 + hh * 8 + tid];
        sm1[tid] = s;
    }
    if (tid < 64) {
        int i = tid >> 3, j = tid & 7;
        float s = 0.0f;
        if (j > i) {
            #pragma unroll
            for (int hh = 0; hh < 3; ++hh) s += m2[n * 192 + hh * 64 + tid];
        }
        sm2[tid] = s;
    }
    if (tid < KNEI + 1) sidx[tid] = le[n * 18 + tid];
    __syncthreads();

    const float* Vb_ = V + (size_t)b * (NNODE * DDIM);
    const float* Ab_ = A + (size_t)b * (NNODE * DDIM);
    const int cen = sidx[0];

    float vn[KNEI], qn[KNEI];
    #pragma unroll
    for (int k = 0; k < KNEI; ++k) {
        int nb = sidx[1 + k];
        float vv = Vb_[nb * DDIM + tid];
        float aa = Ab_[nb * DDIM + tid];
        vn[k] = vv;
        qn[k] = vv + aa;
    }

    float sq = 0.0f, sv = 0.0f;
    #pragma unroll
    for (int k = 0; k < KNEI; ++k) { sq += sm1[k] * qn[k]; sv += sm1[k] * vn[k]; }
    #pragma unroll
    for (int i = 0; i < KNEI; ++i) {
        #pragma unroll
        for (int j = i + 1; j < KNEI; ++j) {
            float w = sm2[i * 8 + j];
            sq += w * fminf(qn[i], qn[j]);
            sv += w * fminf(vn[i], vn[j]);
        }
    }

    float Vc = Vb_[cen * DDIM + tid];
    float Ac = Ab_[cen * DDIM + tid];
    float valq = sq * (1.0f / 3.0f) + (Vc + Ac);
    float valv = sv * (1.0f / 3.0f) + Vc;

    #pragma unroll
    for (int o = 32; o; o >>= 1) {
        valq += __shfl_down(valq, o);
        valv += __shfl_down(valv, o);
    }
    if ((tid & 63) == 0) { pq[tid >> 6] = valq; pv[tid >> 6] = valv; }
    __syncthreads();
    if (tid == 0) {
        out[b * NNODE + n]                = (pq[0] + pq[1]) * (1.0f / 128.0f);
        out[BCNT * NNODE + b * NNODE + n] = (pv[0] + pv[1]) * (1.0f / 128.0f);
    }
}

extern "C" void kernel_launch(void* const* d_in, const int* in_sizes, int n_in,
                              void* d_out, int out_size, void* d_ws, size_t ws_size,
                              hipStream_t stream)
{
    const float* obs  = (const float*)d_in[0];
    const float* act  = (const float*)d_in[1];
    const int*   le   = (const int*)  d_in[2];
    const float* VW1  = (const float*)d_in[3];
    const float* Vb1  = (const float*)d_in[4];
    const float* Vg1  = (const float*)d_in[5];
    const float* Vbe1 = (const float*)d_in[6];
    const float* VW2  = (const float*)d_in[7];
    const float* Vb2  = (const float*)d_in[8];
    const float* AW1  = (const float*)d_in[9];
    const float* Ab1  = (const float*)d_in[10];
    const float* Ag1  = (const float*)d_in[11];
    const float* Abe1 = (const float*)d_in[12];
    const float* AW2  = (const float*)d_in[13];
    const float* Ab2  = (const float*)d_in[14];
    const float* m1   = (const float*)d_in[15];
    const float* m2   = (const float*)d_in[16];
    float* out = (float*)d_out;

    ushort* WFH  = (ushort*)d_ws;
    ushort* WFL  = WFH + WTOT;
    ushort* obsH = WFL + WTOT;
    ushort* obsL = obsH + XPL;
    ushort* actH = obsL + XPL;
    ushort* actL = actH + XPL;
    float*  V    = (float*)(actL + XPL);
    float*  A    = V + (size_t)NR * DDIM;

    wsplit_frag<<<dim3(64, 64), dim3(256), 0, stream>>>(VW1, AW1, VW2, AW2, WFH, WFL);
    xsplit_frag<<<dim3(256, 2), dim3(256), 0, stream>>>(obs, act, obsH, obsL, actH, actL);
    fused_mlp<<<dim3(512), dim3(512), 0, stream>>>(obsH, obsL, actH, actL, WFH, WFL,
                                                   Vb1, Ab1, Vg1, Vbe1, Ag1, Abe1,
                                                   Vb2, Ab2, V, A);
    chi_kernel<<<dim3(NNODE, BCNT), dim3(128), 0, stream>>>(V, A, le, m1, m2, out);
}

// Round 7
// 188.644 us; speedup vs baseline: 1.2302x; 1.0533x over previous
//
#include <hip/hip_runtime.h>
#include <hip/hip_bf16.h>

#define BCNT 128
#define NNODE 64
#define HDIM 256
#define DDIM 128
#define KNEI 8
#define NR (BCNT * NNODE)
#define XPL 2097152ull   // ushorts per X plane: 64n * 8bt * 8kt * 512

typedef __attribute__((ext_vector_type(8))) short bf16x8;
typedef __attribute__((ext_vector_type(8))) unsigned short ushort8;
typedef __attribute__((ext_vector_type(4))) float f32x4;

__device__ __forceinline__ unsigned short f2bf(float f) {
    union { __hip_bfloat16 b; unsigned short u; } c;
    c.b = __float2bfloat16(f);
    return c.u;
}
__device__ __forceinline__ float bf2f(unsigned short u) {
    union { unsigned short u; __hip_bfloat16 b; } c;
    c.u = u;
    return __bfloat162float(c.b);
}
__device__ __forceinline__ void split2(float f, unsigned short& h, unsigned short& l) {
    h = f2bf(f);
    l = f2bf(f - bf2f(h));
}

// ---------------------------------------------------------------------------
// xsplit_frag: X[b][n][k] f32 -> 16-row frag-order bf16 hi/lo planes.
// plane[ ((n*8+bt)*8 + kt)*512 + lane*8 + i ]
//   = X[bt*16 + (lane&15)][n][kt*32 + (lane>>4)*8 + i]
// grid (512 = n*8+bt, 2 = obs/act), 256 thr.
// ---------------------------------------------------------------------------
__global__ __launch_bounds__(256) void xsplit_frag(
    const float* __restrict__ obs, const float* __restrict__ act,
    ushort* __restrict__ obsH, ushort* __restrict__ obsL,
    ushort* __restrict__ actH, ushort* __restrict__ actL)
{
    const int bx = blockIdx.x;
    const int n = bx >> 3, bt = bx & 7;
    const float* S = blockIdx.y ? act : obs;
    ushort* DH = blockIdx.y ? actH : obsH;
    ushort* DL = blockIdx.y ? actL : obsL;

    __shared__ float tile[16][257];
    const int t = threadIdx.x;
    {
        const int r = t >> 4, cs = (t & 15) * 16;
        const float* row = S + ((size_t)(bt * 16 + r) * NNODE + n) * HDIM + cs;
        #pragma unroll
        for (int j = 0; j < 4; ++j) {
            float4 v = *(const float4*)(row + j * 4);
            tile[r][cs + j * 4 + 0] = v.x;
            tile[r][cs + j * 4 + 1] = v.y;
            tile[r][cs + j * 4 + 2] = v.z;
            tile[r][cs + j * 4 + 3] = v.w;
        }
    }
    __syncthreads();
    const int kt = t >> 5, sub = t & 31;
    const int row = sub & 15;
    #pragma unroll
    for (int lg = 0; lg < 2; ++lg) {
        const int lane = lg * 32 + sub;
        const int kg = lane >> 4;          // 0..3
        ushort8 h8, l8;
        #pragma unroll
        for (int i = 0; i < 8; ++i) {
            unsigned short hh, ll;
            split2(tile[row][kt * 32 + kg * 8 + i], hh, ll);
            h8[i] = hh; l8[i] = ll;
        }
        size_t idx = ((((size_t)n * 8 + bt) * 8 + kt) * 512) + (size_t)lane * 8;
        *(ushort8*)(DH + idx) = h8;
        *(ushort8*)(DL + idx) = l8;
    }
}

// ---------------------------------------------------------------------------
// fused_mlp: mlp1 (16x16x32 MFMA, W f32 direct + in-reg split) + LN/ReLU
//            (in-reg + LDS) + mlp2 (hbt in LDS, W2 f32 direct) -> V / A f32.
// Block 512 thr (8 waves) = 16 batch rows, full pipeline for one (n,br,bt).
// Grid 1024; id = bt*128 + pair so the 8 bt-siblings of one (n,br) share an XCD.
// ---------------------------------------------------------------------------
__global__ __launch_bounds__(512, 6) void fused_mlp(
    const ushort* __restrict__ obsH, const ushort* __restrict__ obsL,
    const ushort* __restrict__ actH, const ushort* __restrict__ actL,
    const float* __restrict__ VW1, const float* __restrict__ AW1,
    const float* __restrict__ VW2, const float* __restrict__ AW2,
    const float* __restrict__ Vb1, const float* __restrict__ Ab1,
    const float* __restrict__ Vg1, const float* __restrict__ Vbe1,
    const float* __restrict__ Ag1, const float* __restrict__ Abe1,
    const float* __restrict__ Vb2, const float* __restrict__ Ab2,
    float* __restrict__ Vout, float* __restrict__ Aout)
{
    const int id = blockIdx.x;
    const int bt = id >> 7;              // 0..7 (16 rows each)
    const int pair = id & 127;           // same (pair mod 8) -> same XCD for all bt
    const int n = pair >> 1, br = pair & 1;

    const int t = threadIdx.x;
    const int l = t & 63, w = t >> 6;
    const int l16 = l & 15, g4 = l >> 4;  // g4 0..3

    __shared__ ushort hbtH[16 * 264];
    __shared__ ushort hbtL[16 * 264];
    __shared__ float2 lnS[8][16];
    __shared__ float2 lnp[16];

    // ---- phase 1: h = X @ W1 (wave w -> out cols w*32..w*32+31, 2 tiles) ----
    const int nkt = br ? 16 : 8;
    const float* W1n = br ? (AW1 + (size_t)n * 512 * HDIM)
                          : (VW1 + (size_t)n * 256 * HDIM);
    const int col0 = w * 32 + l16;
    const int col1 = w * 32 + 16 + l16;

    f32x4 aP0 = {}, aQ0 = {}, aP1 = {}, aQ1 = {};
    #pragma unroll 2
    for (int kt = 0; kt < nkt; ++kt) {
        const ushort* xh; const ushort* xl;
        if (br && kt >= 8) { xh = actH; xl = actL; }
        else               { xh = obsH; xl = obsL; }
        const size_t xi = ((((size_t)n * 8 + bt) * 8 + (kt & 7)) * 512) + (size_t)l * 8;
        bf16x8 ah = *(const bf16x8*)(xh + xi);
        bf16x8 al = *(const bf16x8*)(xl + xi);

        const float* wk = W1n + (size_t)(kt * 32 + g4 * 8) * HDIM;
        bf16x8 bh0, bl0, bh1, bl1;
        #pragma unroll
        for (int i = 0; i < 8; ++i) {
            unsigned short hh, ll;
            split2(wk[(size_t)i * HDIM + col0], hh, ll);
            bh0[i] = (short)hh; bl0[i] = (short)ll;
            split2(wk[(size_t)i * HDIM + col1], hh, ll);
            bh1[i] = (short)hh; bl1[i] = (short)ll;
        }
        aP0 = __builtin_amdgcn_mfma_f32_16x16x32_bf16(ah, bh0, aP0, 0, 0, 0);
        aQ0 = __builtin_amdgcn_mfma_f32_16x16x32_bf16(ah, bl0, aQ0, 0, 0, 0);
        aQ0 = __builtin_amdgcn_mfma_f32_16x16x32_bf16(al, bh0, aQ0, 0, 0, 0);
        aP1 = __builtin_amdgcn_mfma_f32_16x16x32_bf16(ah, bh1, aP1, 0, 0, 0);
        aQ1 = __builtin_amdgcn_mfma_f32_16x16x32_bf16(ah, bl1, aQ1, 0, 0, 0);
        aQ1 = __builtin_amdgcn_mfma_f32_16x16x32_bf16(al, bh1, aQ1, 0, 0, 0);
    }

    // ---- phase 2: LN + ReLU + bf16 split -> LDS hbt ----
    const float* b1p = (br ? Ab1 : Vb1) + (size_t)n * HDIM;
    const float bc0 = b1p[col0], bc1 = b1p[col1];
    float v0[4], v1[4];
    {
        float s[4], q[4];
        #pragma unroll
        for (int j = 0; j < 4; ++j) {
            v0[j] = aP0[j] + aQ0[j] + bc0;
            v1[j] = aP1[j] + aQ1[j] + bc1;
            s[j] = v0[j] + v1[j];
            q[j] = v0[j] * v0[j] + v1[j] * v1[j];
        }
        #pragma unroll
        for (int off = 1; off < 16; off <<= 1) {
            #pragma unroll
            for (int j = 0; j < 4; ++j) {
                s[j] += __shfl_xor(s[j], off);
                q[j] += __shfl_xor(q[j], off);
            }
        }
        if (l16 == 0) {
            #pragma unroll
            for (int j = 0; j < 4; ++j) lnS[w][g4 * 4 + j] = float2{s[j], q[j]};
        }
    }
    __syncthreads();
    if (t < 16) {
        float ss = 0.f, qq = 0.f;
        #pragma unroll
        for (int w2 = 0; w2 < 8; ++w2) { ss += lnS[w2][t].x; qq += lnS[w2][t].y; }
        float mu = ss * (1.0f / 256.0f);
        float var = qq * (1.0f / 256.0f) - mu * mu;
        lnp[t] = float2{mu, rsqrtf(var + 1e-5f)};
    }
    __syncthreads();
    {
        const float* gp = br ? Ag1 : Vg1;
        const float* bep = br ? Abe1 : Vbe1;
        const float g0 = gp[col0], g1 = gp[col1];
        const float e0 = bep[col0], e1 = bep[col1];
        #pragma unroll
        for (int j = 0; j < 4; ++j) {
            const int row = g4 * 4 + j;
            float2 p = lnp[row];
            float y0 = fmaxf((v0[j] - p.x) * p.y * g0 + e0, 0.0f);
            float y1 = fmaxf((v1[j] - p.x) * p.y * g1 + e1, 0.0f);
            unsigned short hh, ll;
            split2(y0, hh, ll);
            hbtH[row * 264 + col0] = hh; hbtL[row * 264 + col0] = ll;
            split2(y1, hh, ll);
            hbtH[row * 264 + col1] = hh; hbtL[row * 264 + col1] = ll;
        }
    }
    __syncthreads();

    // ---- phase 3: out = hb @ W2 (wave w -> out cols w*16..w*16+15, full K) ----
    const float* W2n = (br ? AW2 : VW2) + (size_t)n * HDIM * DDIM;
    const int ocol = w * 16 + l16;
    f32x4 cP = {}, cQ = {};
    #pragma unroll 2
    for (int kt = 0; kt < 8; ++kt) {
        const int lb = l16 * 264 + kt * 32 + g4 * 8;
        bf16x8 ah = *(const bf16x8*)&hbtH[lb];
        bf16x8 al = *(const bf16x8*)&hbtL[lb];
        const float* wk = W2n + (size_t)(kt * 32 + g4 * 8) * DDIM;
        bf16x8 bh, bl;
        #pragma unroll
        for (int i = 0; i < 8; ++i) {
            unsigned short hh, ll;
            split2(wk[(size_t)i * DDIM + ocol], hh, ll);
            bh[i] = (short)hh; bl[i] = (short)ll;
        }
        cP = __builtin_amdgcn_mfma_f32_16x16x32_bf16(ah, bh, cP, 0, 0, 0);
        cQ = __builtin_amdgcn_mfma_f32_16x16x32_bf16(ah, bl, cQ, 0, 0, 0);
        cQ = __builtin_amdgcn_mfma_f32_16x16x32_bf16(al, bh, cQ, 0, 0, 0);
    }
    {
        const float b2 = (br ? Ab2 : Vb2)[(size_t)n * DDIM + ocol];
        float* outp = br ? Aout : Vout;
        #pragma unroll
        for (int j = 0; j < 4; ++j) {
            const int brow = bt * 16 + g4 * 4 + j;
            outp[((size_t)brow * NNODE + n) * DDIM + ocol] = cP[j] + cQ[j] + b2;
        }
    }
}

// ---------------------------------------------------------------------------
// chi for both Q=V+A and V; one block per (n, b), 128 threads = one per d
// ---------------------------------------------------------------------------
__global__ __launch_bounds__(128) void chi_kernel(
    const float* __restrict__ V, const float* __restrict__ A,
    const int* __restrict__ le, const float* __restrict__ m1,
    const float* __restrict__ m2, float* __restrict__ out)
{
    const int n = blockIdx.x;
    const int b = blockIdx.y;
    const int tid = threadIdx.x;

    __shared__ float sm1[KNEI];
    __shared__ float sm2[KNEI * KNEI];
    __shared__ int   sidx[KNEI + 1];
    __shared__ float pq[2], pv[2];

    if (tid < KNEI) {
        float s = 0.0f;
        #pragma unroll
        for (int hh = 0; hh < 3; ++hh) s += m1[n * 24 + hh * 8 + tid];
        sm1[tid] = s;
    }
    if (tid < 64) {
        int i = tid >> 3, j = tid & 7;
        float s = 0.0f;
        if (j > i) {
            #pragma unroll
            for (int hh = 0; hh < 3; ++hh) s += m2[n * 192 + hh * 64 + tid];
        }
        sm2[tid] = s;
    }
    if (tid < KNEI + 1) sidx[tid] = le[n * 18 + tid];
    __syncthreads();

    const float* Vb_ = V + (size_t)b * (NNODE * DDIM);
    const float* Ab_ = A + (size_t)b * (NNODE * DDIM);
    const int cen = sidx[0];

    float vn[KNEI], qn[KNEI];
    #pragma unroll
    for (int k = 0; k < KNEI; ++k) {
        int nb = sidx[1 + k];
        float vv = Vb_[nb * DDIM + tid];
        float aa = Ab_[nb * DDIM + tid];
        vn[k] = vv;
        qn[k] = vv + aa;
    }

    float sq = 0.0f, sv = 0.0f;
    #pragma unroll
    for (int k = 0; k < KNEI; ++k) { sq += sm1[k] * qn[k]; sv += sm1[k] * vn[k]; }
    #pragma unroll
    for (int i = 0; i < KNEI; ++i) {
        #pragma unroll
        for (int j = i + 1; j < KNEI; ++j) {
            float w = sm2[i * 8 + j];
            sq += w * fminf(qn[i], qn[j]);
            sv += w * fminf(vn[i], vn[j]);
        }
    }

    float Vc = Vb_[cen * DDIM + tid];
    float Ac = Ab_[cen * DDIM + tid];
    float valq = sq * (1.0f / 3.0f) + (Vc + Ac);
    float valv = sv * (1.0f / 3.0f) + Vc;

    #pragma unroll
    for (int o = 32; o; o >>= 1) {
        valq += __shfl_down(valq, o);
        valv += __shfl_down(valv, o);
    }
    if ((tid & 63) == 0) { pq[tid >> 6] = valq; pv[tid >> 6] = valv; }
    __syncthreads();
    if (tid == 0) {
        out[b * NNODE + n]                = (pq[0] + pq[1]) * (1.0f / 128.0f);
        out[BCNT * NNODE + b * NNODE + n] = (pv[0] + pv[1]) * (1.0f / 128.0f);
    }
}

extern "C" void kernel_launch(void* const* d_in, const int* in_sizes, int n_in,
                              void* d_out, int out_size, void* d_ws, size_t ws_size,
                              hipStream_t stream)
{
    const float* obs  = (const float*)d_in[0];
    const float* act  = (const float*)d_in[1];
    const int*   le   = (const int*)  d_in[2];
    const float* VW1  = (const float*)d_in[3];
    const float* Vb1  = (const float*)d_in[4];
    const float* Vg1  = (const float*)d_in[5];
    const float* Vbe1 = (const float*)d_in[6];
    const float* VW2  = (const float*)d_in[7];
    const float* Vb2  = (const float*)d_in[8];
    const float* AW1  = (const float*)d_in[9];
    const float* Ab1  = (const float*)d_in[10];
    const float* Ag1  = (const float*)d_in[11];
    const float* Abe1 = (const float*)d_in[12];
    const float* AW2  = (const float*)d_in[13];
    const float* Ab2  = (const float*)d_in[14];
    const float* m1   = (const float*)d_in[15];
    const float* m2   = (const float*)d_in[16];
    float* out = (float*)d_out;

    ushort* obsH = (ushort*)d_ws;
    ushort* obsL = obsH + XPL;
    ushort* actH = obsL + XPL;
    ushort* actL = actH + XPL;
    float*  V    = (float*)(actL + XPL);
    float*  A    = V + (size_t)NR * DDIM;

    xsplit_frag<<<dim3(512, 2), dim3(256), 0, stream>>>(obs, act, obsH, obsL, actH, actL);
    fused_mlp<<<dim3(1024), dim3(512), 0, stream>>>(obsH, obsL, actH, actL,
                                                    VW1, AW1, VW2, AW2,
                                                    Vb1, Ab1, Vg1, Vbe1, Ag1, Abe1,
                                                    Vb2, Ab2, V, A);
    chi_kernel<<<dim3(NNODE, BCNT), dim3(128), 0, stream>>>(V, A, le, m1, m2, out);
}